// Round 2
// baseline (787.239 us; speedup 1.0000x reference)
//
#include <hip/hip_runtime.h>
#include <hip/hip_bf16.h>
#include <cstdint>

#define BB 32
#define NN 577
#define CC 768
#define HH 12
#define HIDN 3072
#define MROWS (BB*NN)   // 18464

typedef __attribute__((ext_vector_type(8))) short bf16x8;   // 8 bf16 = 4 VGPRs
typedef __attribute__((ext_vector_type(4))) float f32x4;

__device__ __forceinline__ float b2f(unsigned short u) {
    union { float f; unsigned int i; } x; x.i = ((unsigned int)u) << 16; return x.f;
}
__device__ __forceinline__ unsigned short f2b(float f) {
    union { float f; unsigned int i; } x; x.f = f;
    unsigned int i = x.i;
    i += 0x7fffu + ((i >> 16) & 1u);   // round-to-nearest-even
    return (unsigned short)(i >> 16);
}

__device__ __forceinline__ void async16(const void* g, void* l) {
    __builtin_amdgcn_global_load_lds(
        (const __attribute__((address_space(1))) uint32_t*)g,
        (__attribute__((address_space(3))) uint32_t*)l, 16, 0, 0);
}

// Fast exact-GELU: erf via Abramowitz-Stegun 7.1.26 (|err|<=1.5e-7),
// rcp + exp are single HW instrs. ~13 VALU vs ~45 for libm erff.
__device__ __forceinline__ float gelu_f(float v) {
    float ax = fabsf(v) * 0.70710678118654752f;
    float t = __builtin_amdgcn_rcpf(1.0f + 0.3275911f * ax);
    float poly = t * (0.254829592f + t * (-0.284496736f + t * (1.421413741f +
                 t * (-1.453152027f + t * 1.061405429f))));
    float e = __expf(-ax * ax);
    float erf_abs = 1.0f - poly * e;
    float erf_v = (v >= 0.f) ? erf_abs : -erf_abs;
    return 0.5f * v * (1.0f + erf_v);
}

// ---------------------------------------------------------------------------
// fp32 -> bf16 weight conversion (4 matrices in one kernel)
// ---------------------------------------------------------------------------
__global__ void cvt4(const float* __restrict__ a, int na, unsigned short* __restrict__ oa,
                     const float* __restrict__ b, int nb, unsigned short* __restrict__ ob,
                     const float* __restrict__ c, int nc, unsigned short* __restrict__ oc,
                     const float* __restrict__ d, int nd, unsigned short* __restrict__ od) {
    int stride = gridDim.x * blockDim.x;
    int t = blockIdx.x * blockDim.x + threadIdx.x;
    for (int i = t; i < na; i += stride) oa[i] = f2b(a[i]);
    for (int i = t; i < nb; i += stride) ob[i] = f2b(b[i]);
    for (int i = t; i < nc; i += stride) oc[i] = f2b(c[i]);
    for (int i = t; i < nd; i += stride) od[i] = f2b(d[i]);
}

// ---------------------------------------------------------------------------
// LayerNorm (row of 768), fp32 in -> bf16 out
// ---------------------------------------------------------------------------
__global__ __launch_bounds__(256)
void ln_kernel(const float* __restrict__ x, const float* __restrict__ w,
               const float* __restrict__ bsv, unsigned short* __restrict__ out) {
    int row = blockIdx.x;
    const float* xr = x + (size_t)row * CC;
    float v[3]; float s = 0.f, ss = 0.f;
    #pragma unroll
    for (int i = 0; i < 3; ++i) {
        v[i] = xr[threadIdx.x + i * 256];
        s += v[i]; ss += v[i] * v[i];
    }
    int lane = threadIdx.x & 63, wv = threadIdx.x >> 6;
    #pragma unroll
    for (int off = 32; off; off >>= 1) { s += __shfl_down(s, off); ss += __shfl_down(ss, off); }
    __shared__ float rs[4], rss[4];
    __shared__ float mean_s, rstd_s;
    if (lane == 0) { rs[wv] = s; rss[wv] = ss; }
    __syncthreads();
    if (threadIdx.x == 0) {
        float S = rs[0] + rs[1] + rs[2] + rs[3];
        float SS = rss[0] + rss[1] + rss[2] + rss[3];
        float m = S * (1.0f / 768.0f);
        float var = SS * (1.0f / 768.0f) - m * m;
        mean_s = m; rstd_s = rsqrtf(var + 1e-6f);
    }
    __syncthreads();
    float m = mean_s, r = rstd_s;
    #pragma unroll
    for (int i = 0; i < 3; ++i) {
        int c = threadIdx.x + i * 256;
        out[(size_t)row * CC + c] = f2b((v[i] - m) * r * w[c] + bsv[c]);
    }
}

// ---------------------------------------------------------------------------
// bf16 GEMM: out = epilogue(A(M,K) @ Bw(N,K)^T + bias)
// m97 structure, BK=64 as two 32-wide panels (As[2]/Bs[2], 32 KB LDS):
// halves the vmcnt(0)+barrier drains per FLOP; per-panel LDS indexing is
// byte-identical to the verified m97 pattern. K must be a multiple of 64.
// EPI 0: bf16 store | 1: fast exact GELU -> bf16 | 2: fp32 store w/ residual
// XCD swizzle: n-tiles sharing an m-row get block IDs == same value mod 8 so
// they land on one XCD -> A k-slices stay L2-resident (FETCH near-ideal, R4).
// Launch grid dim3(NT, 152): 152 = 8*ceil(145/8) padded m-rows.
// ---------------------------------------------------------------------------
template <int EPI>
__global__ __launch_bounds__(256)
void gemm_bt(const unsigned short* __restrict__ A, const unsigned short* __restrict__ Bw,
             const float* __restrict__ bias, const float* __restrict__ resid,
             unsigned short* __restrict__ outb, float* __restrict__ outf,
             int M, int N, int K) {
    const int NT = gridDim.x;
    const int MT = (M + 127) >> 7;
    // dispatch-order flat id -> (m_tile, n_tile) with same-XCD A sharing
    int flat = blockIdx.y * NT + blockIdx.x;
    int xcd = flat & 7, s = flat >> 3;
    int n_t = s % NT, mj = s / NT;
    int m_t = xcd + 8 * mj;
    if (m_t >= MT) return;
    const int m0 = m_t * 128, n0 = n_t * 128;

    __shared__ __align__(16) unsigned short As[2][128 * 32];
    __shared__ __align__(16) unsigned short Bs[2][128 * 32];
    const int tid = threadIdx.x;
    const int wave = tid >> 6, lane = tid & 63;
    const int wr = wave >> 1, wc = wave & 1;
    const int quad = lane >> 4, l16 = lane & 15;

    f32x4 acc[4][4] = {};

    // per-thread staging coords (fixed across K): two chunks per panel/matrix
    const int c0 = tid, c1 = 256 + tid;
    const int row0 = c0 >> 2, seg0 = c0 & 3;
    const int row1 = c1 >> 2, seg1 = c1 & 3;
    int gm0 = m0 + row0; if (gm0 > M - 1) gm0 = M - 1;
    int gm1 = m0 + row1; if (gm1 > M - 1) gm1 = M - 1;
    const unsigned short* a0 = A + (size_t)gm0 * K + seg0 * 8;
    const unsigned short* a1 = A + (size_t)gm1 * K + seg1 * 8;
    const unsigned short* b0 = Bw + (size_t)(n0 + row0) * K + seg0 * 8;
    const unsigned short* b1 = Bw + (size_t)(n0 + row1) * K + seg1 * 8;

    for (int k0 = 0; k0 < K; k0 += 64) {
        #pragma unroll
        for (int p = 0; p < 2; ++p) {
            int kk = k0 + p * 32;
            async16(a0 + kk, &As[p][c0 * 8]);
            async16(a1 + kk, &As[p][c1 * 8]);
            async16(b0 + kk, &Bs[p][c0 * 8]);
            async16(b1 + kk, &Bs[p][c1 * 8]);
        }
        __syncthreads();
        #pragma unroll
        for (int p = 0; p < 2; ++p) {
            bf16x8 af[4], bfr[4];
            #pragma unroll
            for (int mi = 0; mi < 4; ++mi)
                af[mi] = *(const bf16x8*)&As[p][(wr * 64 + mi * 16 + l16) * 32 + quad * 8];
            #pragma unroll
            for (int ni = 0; ni < 4; ++ni)
                bfr[ni] = *(const bf16x8*)&Bs[p][(wc * 64 + ni * 16 + l16) * 32 + quad * 8];
            #pragma unroll
            for (int mi = 0; mi < 4; ++mi)
                #pragma unroll
                for (int ni = 0; ni < 4; ++ni)
                    acc[mi][ni] = __builtin_amdgcn_mfma_f32_16x16x32_bf16(af[mi], bfr[ni], acc[mi][ni], 0, 0, 0);
        }
        __syncthreads();
    }

    #pragma unroll
    for (int mi = 0; mi < 4; ++mi) {
        #pragma unroll
        for (int r = 0; r < 4; ++r) {
            int grow = m0 + wr * 64 + mi * 16 + quad * 4 + r;   // C/D: row=quad*4+reg
            if (grow >= M) continue;
            #pragma unroll
            for (int ni = 0; ni < 4; ++ni) {
                int gcol = n0 + wc * 64 + ni * 16 + l16;        // C/D: col=lane&15
                float v = acc[mi][ni][r] + bias[gcol];
                size_t idx = (size_t)grow * N + gcol;
                if (EPI == 0) {
                    outb[idx] = f2b(v);
                } else if (EPI == 1) {
                    outb[idx] = f2b(gelu_f(v));
                } else {
                    outf[idx] = resid[idx] + v;
                }
            }
        }
    }
}

// ---------------------------------------------------------------------------
// MFMA flash attention, v2.1. One block = (b, h, 64 q rows); 4 waves x 16 rows.
// Vt uses a key-group XOR swizzle (group' = (key>>3) ^ (d>>3)) so the
// transpose's u16 writes are bank-conflict-free (was 16-way); reads remain
// aligned b128 at the same cost.
// ---------------------------------------------------------------------------
__global__ __launch_bounds__(256)
void attn_mfma(const unsigned short* __restrict__ qkv, const float* __restrict__ aw,
               unsigned short* __restrict__ O, float* __restrict__ patch) {
    const int qt = blockIdx.x, h = blockIdx.y, b = blockIdx.z;
    const int tid = threadIdx.x, wv = tid >> 6, lane = tid & 63;
    const int quad = lane >> 4, l16 = lane & 15;

    __shared__ __align__(16) unsigned short Ks[64 * 72];
    __shared__ __align__(16) unsigned short Vt[64 * 72];
    __shared__ __align__(16) unsigned short Pt[4][64 * 18];
    __shared__ __align__(16) float Sw[4][16 * 68];

    // Q fragment (A-layout: m=l16, k=quad*8+j), resident all kernel.
    int qrow = qt * 64 + wv * 16 + l16;
    int qclamp = qrow < NN ? qrow : NN - 1;
    const unsigned short* qbase = qkv + (size_t)(b * NN + qclamp) * 2304 + h * 64;
    bf16x8 qf[2];
    qf[0] = *(const bf16x8*)(qbase + quad * 8);
    qf[1] = *(const bf16x8*)(qbase + 32 + quad * 8);

    f32x4 o[4] = {};          // O accumulator, C-layout (row=quad*4+r, col d=ni*16+l16)
    float mst = -1.0e30f;     // running max for row l16 (replicated across quads)
    float lst = 0.f;          // running denom for row l16

    for (int kt = 0; kt < 10; ++kt) {
        __syncthreads();   // previous tile's Ks/Vt reads done before overwrite
        // ---- stage K tile [key][d] and V tile transposed+swizzled [d][key'] ----
        #pragma unroll
        for (int i = 0; i < 2; ++i) {
            int c = i * 256 + tid;
            int key = c >> 3, seg = c & 7;           // 8 segs of 8 bf16 per 64-elem row
            int gk = kt * 64 + key; if (gk >= NN) gk = NN - 1;
            const unsigned short* kb = qkv + (size_t)(b * NN + gk) * 2304 + 768 + h * 64 + seg * 8;
            bf16x8 kv = *(const bf16x8*)kb;
            *(bf16x8*)&Ks[key * 72 + seg * 8] = kv;
            const unsigned short* vb = qkv + (size_t)(b * NN + gk) * 2304 + 1536 + h * 64 + seg * 8;
            bf16x8 vvv = *(const bf16x8*)vb;
            int kg = key >> 3, kl = key & 7;
            int swz = (kg ^ seg) * 8 + kl;           // d>>3 == seg for d=seg*8+e
            #pragma unroll
            for (int e = 0; e < 8; ++e)
                Vt[(seg * 8 + e) * 72 + swz] = ((const unsigned short*)&vvv)[e];
        }
        __syncthreads();

        // ---- S = Q K^T  (16 q x 64 keys per wave) ----
        f32x4 s[4];
        #pragma unroll
        for (int ni = 0; ni < 4; ++ni) {
            bf16x8 b0 = *(const bf16x8*)&Ks[(ni * 16 + l16) * 72 + quad * 8];
            bf16x8 b1 = *(const bf16x8*)&Ks[(ni * 16 + l16) * 72 + 32 + quad * 8];
            f32x4 acc = {};
            acc = __builtin_amdgcn_mfma_f32_16x16x32_bf16(qf[0], b0, acc, 0, 0, 0);
            acc = __builtin_amdgcn_mfma_f32_16x16x32_bf16(qf[1], b1, acc, 0, 0, 0);
            s[ni] = acc;
        }

        // ---- store scores (scaled) to Sw via verified C/D mapping ----
        float* SwW = Sw[wv];
        #pragma unroll
        for (int ni = 0; ni < 4; ++ni)
            #pragma unroll
            for (int r = 0; r < 4; ++r)
                SwW[(quad * 4 + r) * 68 + ni * 16 + l16] = s[ni][r] * 0.125f;

        // ---- mask invalid keys (only last tile has any) ----
        if (kt == 9) {
            #pragma unroll
            for (int j = 0; j < 16; ++j) {
                int gkey = kt * 64 + quad * 16 + j;
                if (gkey >= NN) SwW[l16 * 68 + quad * 16 + j] = -1.0e30f;
            }
        }

        // ---- row 0 only: patch_attn extraction + attn_weight factor ----
        if (qt == 0 && wv == 0 && l16 == 0) {
            #pragma unroll
            for (int j = 0; j < 16; ++j) {
                int gkey = kt * 64 + quad * 16 + j;
                if (gkey >= 1 && gkey < NN) {
                    float v = SwW[0 * 68 + quad * 16 + j];
                    patch[(size_t)(b * HH + h) * (NN - 1) + gkey - 1] = v;
                    float f = aw[b * (NN - 1) + gkey - 1] * 0.1f + 0.9f;
                    SwW[0 * 68 + quad * 16 + j] = v * f;
                }
            }
        }

        // ---- online softmax: lane owns row l16, keys quad*16..+15 ----
        const float* Srow = &SwW[l16 * 68];
        float tm = -1.0e30f;
        #pragma unroll
        for (int j = 0; j < 16; ++j) tm = fmaxf(tm, Srow[quad * 16 + j]);
        tm = fmaxf(tm, __shfl_xor(tm, 16));
        tm = fmaxf(tm, __shfl_xor(tm, 32));
        float nm = fmaxf(mst, tm);
        float alpha = __expf(mst - nm);     // first tile: exp(-1e30) -> 0
        mst = nm;
        float rsum = 0.f;
        #pragma unroll
        for (int j = 0; j < 16; ++j) {
            float p = __expf(Srow[quad * 16 + j] - nm);   // masked: exp(-1e30) -> 0
            Pt[wv][(quad * 16 + j) * 18 + l16] = f2b(p);
            rsum += p;
        }
        rsum += __shfl_xor(rsum, 16);
        rsum += __shfl_xor(rsum, 32);
        lst = lst * alpha + rsum;

        // ---- rescale O rows by alpha (alpha for row quad*4+r from lane quad*4+r) ----
        #pragma unroll
        for (int r = 0; r < 4; ++r) {
            float ar = __shfl(alpha, quad * 4 + r);
            #pragma unroll
            for (int ni = 0; ni < 4; ++ni) o[ni][r] *= ar;
        }

        // ---- O += P V ----
        #pragma unroll
        for (int kc = 0; kc < 2; ++kc) {
            union { bf16x8 v; unsigned short u[8]; } af;
            #pragma unroll
            for (int j = 0; j < 8; ++j)
                af.u[j] = Pt[wv][(kc * 32 + quad * 8 + j) * 18 + l16];
            #pragma unroll
            for (int ni = 0; ni < 4; ++ni) {
                int d = ni * 16 + l16;
                int gs = (kc * 4 + quad) ^ (d >> 3);   // un-swizzle key group
                bf16x8 vf = *(const bf16x8*)&Vt[d * 72 + gs * 8];
                o[ni] = __builtin_amdgcn_mfma_f32_16x16x32_bf16(af.v, vf, o[ni], 0, 0, 0);
            }
        }
    }

    // ---- finalize: O /= l (l for row quad*4+r from lane quad*4+r), store bf16 ----
    #pragma unroll
    for (int r = 0; r < 4; ++r) {
        float lr = __shfl(lst, quad * 4 + r);
        float inv = (lr > 0.f) ? __builtin_amdgcn_rcpf(lr) : 0.f;
        int row = qt * 64 + wv * 16 + quad * 4 + r;
        if (row < NN) {
            #pragma unroll
            for (int ni = 0; ni < 4; ++ni)
                O[(size_t)(b * NN + row) * CC + h * 64 + ni * 16 + l16] = f2b(o[ni][r] * inv);
        }
    }
}

// ---------------------------------------------------------------------------
extern "C" void kernel_launch(void* const* d_in, const int* in_sizes, int n_in,
                              void* d_out, int out_size, void* d_ws, size_t ws_size,
                              hipStream_t stream) {
    const float* x       = (const float*)d_in[0];
    const float* aw      = (const float*)d_in[1];
    const float* ln1w    = (const float*)d_in[2];
    const float* ln1b    = (const float*)d_in[3];
    const float* qkvw_f  = (const float*)d_in[4];
    const float* qkvb    = (const float*)d_in[5];
    const float* projw_f = (const float*)d_in[6];
    const float* projb   = (const float*)d_in[7];
    const float* ln2w    = (const float*)d_in[8];
    const float* ln2b    = (const float*)d_in[9];
    const float* fc1w_f  = (const float*)d_in[10];
    const float* fc1b    = (const float*)d_in[11];
    const float* fc2w_f  = (const float*)d_in[12];
    const float* fc2b    = (const float*)d_in[13];

    // workspace layout (g1 aliases h_bf+qkv, both dead before FC1). ~240 MB.
    char* ws = (char*)d_ws;
    unsigned short* h_bf  = (unsigned short*)(ws + 0);            // 18464x768 bf16
    unsigned short* qkv   = (unsigned short*)(ws + 28360704);     // 18464x2304 bf16
    unsigned short* g1    = (unsigned short*)(ws + 0);            // 18464x3072 bf16 (alias)
    unsigned short* attno = (unsigned short*)(ws + 113442816);    // 18464x768 bf16
    float*          x1    = (float*)(ws + 141803520);             // 18464x768 f32
    unsigned short* h2    = (unsigned short*)(ws + 198524928);    // 18464x768 bf16
    unsigned short* qkvw  = (unsigned short*)(ws + 226885632);    // 2304x768 bf16
    unsigned short* projw = (unsigned short*)(ws + 230424576);    // 768x768 bf16
    unsigned short* fc1w  = (unsigned short*)(ws + 231604224);    // 3072x768 bf16
    unsigned short* fc2w  = (unsigned short*)(ws + 236322816);    // 768x3072 bf16

    float* out_x = (float*)d_out;
    float* out_patch = out_x + (size_t)MROWS * CC;

    // 152 = 8 * ceil(145 m-tiles / 8) -- padded for the XCD swizzle
    cvt4<<<1024, 256, 0, stream>>>(qkvw_f, 2304 * 768, qkvw,
                                   projw_f, 768 * 768, projw,
                                   fc1w_f, 3072 * 768, fc1w,
                                   fc2w_f, 768 * 3072, fc2w);
    ln_kernel<<<MROWS, 256, 0, stream>>>(x, ln1w, ln1b, h_bf);
    gemm_bt<0><<<dim3(18, 152), 256, 0, stream>>>(h_bf, qkvw, qkvb, nullptr, qkv, nullptr,
                                                  MROWS, 2304, 768);
    attn_mfma<<<dim3(10, HH, BB), 256, 0, stream>>>(qkv, aw, attno, out_patch);
    gemm_bt<2><<<dim3(6, 152), 256, 0, stream>>>(attno, projw, projb, x, nullptr, x1,
                                                 MROWS, 768, 768);
    ln_kernel<<<MROWS, 256, 0, stream>>>(x1, ln2w, ln2b, h2);
    gemm_bt<1><<<dim3(24, 152), 256, 0, stream>>>(h2, fc1w, fc1b, nullptr, g1, nullptr,
                                                  MROWS, 3072, 768);
    gemm_bt<2><<<dim3(6, 152), 256, 0, stream>>>(g1, fc2w, fc2b, x1, nullptr, out_x,
                                                 MROWS, 768, 3072);
}

// Round 3
// 752.111 us; speedup vs baseline: 1.0467x; 1.0467x over previous
//
#include <hip/hip_runtime.h>
#include <hip/hip_bf16.h>
#include <cstdint>

#define BB 32
#define NN 577
#define CC 768
#define HH 12
#define HIDN 3072
#define MROWS (BB*NN)   // 18464

typedef __attribute__((ext_vector_type(8))) short bf16x8;   // 8 bf16 = 4 VGPRs
typedef __attribute__((ext_vector_type(4))) float f32x4;

__device__ __forceinline__ float b2f(unsigned short u) {
    union { float f; unsigned int i; } x; x.i = ((unsigned int)u) << 16; return x.f;
}
__device__ __forceinline__ unsigned short f2b(float f) {
    union { float f; unsigned int i; } x; x.f = f;
    unsigned int i = x.i;
    i += 0x7fffu + ((i >> 16) & 1u);   // round-to-nearest-even
    return (unsigned short)(i >> 16);
}

__device__ __forceinline__ void async16(const void* g, void* l) {
    __builtin_amdgcn_global_load_lds(
        (const __attribute__((address_space(1))) uint32_t*)g,
        (__attribute__((address_space(3))) uint32_t*)l, 16, 0, 0);
}

// Fast exact-GELU: erf via Abramowitz-Stegun 7.1.26 (|err|<=1.5e-7),
// rcp + exp are single HW instrs. ~13 VALU vs ~45 for libm erff.
__device__ __forceinline__ float gelu_f(float v) {
    float ax = fabsf(v) * 0.70710678118654752f;
    float t = __builtin_amdgcn_rcpf(1.0f + 0.3275911f * ax);
    float poly = t * (0.254829592f + t * (-0.284496736f + t * (1.421413741f +
                 t * (-1.453152027f + t * 1.061405429f))));
    float e = __expf(-ax * ax);
    float erf_abs = 1.0f - poly * e;
    float erf_v = (v >= 0.f) ? erf_abs : -erf_abs;
    return 0.5f * v * (1.0f + erf_v);
}

// ---------------------------------------------------------------------------
// fp32 -> bf16 weight conversion (4 matrices in one kernel)
// ---------------------------------------------------------------------------
__global__ void cvt4(const float* __restrict__ a, int na, unsigned short* __restrict__ oa,
                     const float* __restrict__ b, int nb, unsigned short* __restrict__ ob,
                     const float* __restrict__ c, int nc, unsigned short* __restrict__ oc,
                     const float* __restrict__ d, int nd, unsigned short* __restrict__ od) {
    int stride = gridDim.x * blockDim.x;
    int t = blockIdx.x * blockDim.x + threadIdx.x;
    for (int i = t; i < na; i += stride) oa[i] = f2b(a[i]);
    for (int i = t; i < nb; i += stride) ob[i] = f2b(b[i]);
    for (int i = t; i < nc; i += stride) oc[i] = f2b(c[i]);
    for (int i = t; i < nd; i += stride) od[i] = f2b(d[i]);
}

// ---------------------------------------------------------------------------
// LayerNorm (row of 768), fp32 in -> bf16 out
// ---------------------------------------------------------------------------
__global__ __launch_bounds__(256)
void ln_kernel(const float* __restrict__ x, const float* __restrict__ w,
               const float* __restrict__ bsv, unsigned short* __restrict__ out) {
    int row = blockIdx.x;
    const float* xr = x + (size_t)row * CC;
    float v[3]; float s = 0.f, ss = 0.f;
    #pragma unroll
    for (int i = 0; i < 3; ++i) {
        v[i] = xr[threadIdx.x + i * 256];
        s += v[i]; ss += v[i] * v[i];
    }
    int lane = threadIdx.x & 63, wv = threadIdx.x >> 6;
    #pragma unroll
    for (int off = 32; off; off >>= 1) { s += __shfl_down(s, off); ss += __shfl_down(ss, off); }
    __shared__ float rs[4], rss[4];
    __shared__ float mean_s, rstd_s;
    if (lane == 0) { rs[wv] = s; rss[wv] = ss; }
    __syncthreads();
    if (threadIdx.x == 0) {
        float S = rs[0] + rs[1] + rs[2] + rs[3];
        float SS = rss[0] + rss[1] + rss[2] + rss[3];
        float m = S * (1.0f / 768.0f);
        float var = SS * (1.0f / 768.0f) - m * m;
        mean_s = m; rstd_s = rsqrtf(var + 1e-6f);
    }
    __syncthreads();
    float m = mean_s, r = rstd_s;
    #pragma unroll
    for (int i = 0; i < 3; ++i) {
        int c = threadIdx.x + i * 256;
        out[(size_t)row * CC + c] = f2b((v[i] - m) * r * w[c] + bsv[c]);
    }
}

// ---------------------------------------------------------------------------
// bf16 GEMM: out = epilogue(A(M,K) @ Bw(N,K)^T + bias)
// m97 structure, BK=64 as two 32-wide panels (As[2]/Bs[2], 32 KB LDS):
// halves the vmcnt(0)+barrier drains per FLOP; per-panel LDS indexing is
// byte-identical to the verified m97 pattern. K must be a multiple of 64.
// EPI 0: bf16 store | 1: fast exact GELU -> bf16 | 2: fp32 store w/ residual
// XCD swizzle: n-tiles sharing an m-row get block IDs == same value mod 8 so
// they land on one XCD -> A k-slices stay L2-resident (FETCH near-ideal, R4).
// Launch grid dim3(NT, 152): 152 = 8*ceil(145/8) padded m-rows.
// ---------------------------------------------------------------------------
template <int EPI>
__global__ __launch_bounds__(256)
void gemm_bt(const unsigned short* __restrict__ A, const unsigned short* __restrict__ Bw,
             const float* __restrict__ bias, const float* __restrict__ resid,
             unsigned short* __restrict__ outb, float* __restrict__ outf,
             int M, int N, int K) {
    const int NT = gridDim.x;
    const int MT = (M + 127) >> 7;
    // dispatch-order flat id -> (m_tile, n_tile) with same-XCD A sharing
    int flat = blockIdx.y * NT + blockIdx.x;
    int xcd = flat & 7, s = flat >> 3;
    int n_t = s % NT, mj = s / NT;
    int m_t = xcd + 8 * mj;
    if (m_t >= MT) return;
    const int m0 = m_t * 128, n0 = n_t * 128;

    __shared__ __align__(16) unsigned short As[2][128 * 32];
    __shared__ __align__(16) unsigned short Bs[2][128 * 32];
    const int tid = threadIdx.x;
    const int wave = tid >> 6, lane = tid & 63;
    const int wr = wave >> 1, wc = wave & 1;
    const int quad = lane >> 4, l16 = lane & 15;

    f32x4 acc[4][4] = {};

    // per-thread staging coords (fixed across K): two chunks per panel/matrix
    const int c0 = tid, c1 = 256 + tid;
    const int row0 = c0 >> 2, seg0 = c0 & 3;
    const int row1 = c1 >> 2, seg1 = c1 & 3;
    int gm0 = m0 + row0; if (gm0 > M - 1) gm0 = M - 1;
    int gm1 = m0 + row1; if (gm1 > M - 1) gm1 = M - 1;
    const unsigned short* a0 = A + (size_t)gm0 * K + seg0 * 8;
    const unsigned short* a1 = A + (size_t)gm1 * K + seg1 * 8;
    const unsigned short* b0 = Bw + (size_t)(n0 + row0) * K + seg0 * 8;
    const unsigned short* b1 = Bw + (size_t)(n0 + row1) * K + seg1 * 8;

    for (int k0 = 0; k0 < K; k0 += 64) {
        #pragma unroll
        for (int p = 0; p < 2; ++p) {
            int kk = k0 + p * 32;
            async16(a0 + kk, &As[p][c0 * 8]);
            async16(a1 + kk, &As[p][c1 * 8]);
            async16(b0 + kk, &Bs[p][c0 * 8]);
            async16(b1 + kk, &Bs[p][c1 * 8]);
        }
        __syncthreads();
        #pragma unroll
        for (int p = 0; p < 2; ++p) {
            bf16x8 af[4], bfr[4];
            #pragma unroll
            for (int mi = 0; mi < 4; ++mi)
                af[mi] = *(const bf16x8*)&As[p][(wr * 64 + mi * 16 + l16) * 32 + quad * 8];
            #pragma unroll
            for (int ni = 0; ni < 4; ++ni)
                bfr[ni] = *(const bf16x8*)&Bs[p][(wc * 64 + ni * 16 + l16) * 32 + quad * 8];
            #pragma unroll
            for (int mi = 0; mi < 4; ++mi)
                #pragma unroll
                for (int ni = 0; ni < 4; ++ni)
                    acc[mi][ni] = __builtin_amdgcn_mfma_f32_16x16x32_bf16(af[mi], bfr[ni], acc[mi][ni], 0, 0, 0);
        }
        __syncthreads();
    }

    #pragma unroll
    for (int mi = 0; mi < 4; ++mi) {
        #pragma unroll
        for (int r = 0; r < 4; ++r) {
            int grow = m0 + wr * 64 + mi * 16 + quad * 4 + r;   // C/D: row=quad*4+reg
            if (grow >= M) continue;
            #pragma unroll
            for (int ni = 0; ni < 4; ++ni) {
                int gcol = n0 + wc * 64 + ni * 16 + l16;        // C/D: col=lane&15
                float v = acc[mi][ni][r] + bias[gcol];
                size_t idx = (size_t)grow * N + gcol;
                if (EPI == 0) {
                    outb[idx] = f2b(v);
                } else if (EPI == 1) {
                    outb[idx] = f2b(gelu_f(v));
                } else {
                    outf[idx] = resid[idx] + v;
                }
            }
        }
    }
}

// ---------------------------------------------------------------------------
// MFMA flash attention, v3: in-register online softmax.
// One block = (b, h, 64 q rows); 4 waves x 16 rows.
// S stays in the MFMA C/D register layout (lane quad,l16 holds
// S[row=quad*4+r][key=ni*16+l16]); row stats via intra-quad shfl_xor
// butterfly (16 lanes own all 64 keys of rows quad*4..quad*4+3).
// 0.125 scale folded into Q at load (power of 2 -> exact in bf16).
// P transposed for the PV A-fragment through Pt[row][key] (pitch 72):
// u16 scatter writes are 2-way (free), reads are one aligned b128 per kc.
// Kills the old Sw f32 round-trip (32 8-way-conflicted scalar reads/lane).
// LDS 45KB -> 27.6KB: 3 -> 5 blocks/CU.
// ---------------------------------------------------------------------------
__global__ __launch_bounds__(256)
void attn_mfma(const unsigned short* __restrict__ qkv, const float* __restrict__ aw,
               unsigned short* __restrict__ O, float* __restrict__ patch) {
    const int qt = blockIdx.x, h = blockIdx.y, b = blockIdx.z;
    const int tid = threadIdx.x, wv = tid >> 6, lane = tid & 63;
    const int quad = lane >> 4, l16 = lane & 15;

    __shared__ __align__(16) unsigned short Ks[64 * 72];
    __shared__ __align__(16) unsigned short Vt[64 * 72];
    __shared__ __align__(16) unsigned short Pt[4][16 * 72];

    // Q fragment (A-layout: m=l16, k=quad*8+j), resident, pre-scaled by 2^-3.
    int qrow = qt * 64 + wv * 16 + l16;
    int qclamp = qrow < NN ? qrow : NN - 1;
    const unsigned short* qbase = qkv + (size_t)(b * NN + qclamp) * 2304 + h * 64;
    bf16x8 qf[2];
    qf[0] = *(const bf16x8*)(qbase + quad * 8);
    qf[1] = *(const bf16x8*)(qbase + 32 + quad * 8);
    #pragma unroll
    for (int i = 0; i < 2; ++i) {
        union { bf16x8 v; unsigned short u[8]; } t; t.v = qf[i];
        #pragma unroll
        for (int j = 0; j < 8; ++j) t.u[j] = f2b(b2f(t.u[j]) * 0.125f);
        qf[i] = t.v;
    }

    f32x4 o[4] = {};          // O accumulator, C-layout (row=quad*4+r, col d=ni*16+l16)
    float mst[4], lst[4];     // per-row running max / denom (rows quad*4+r)
    #pragma unroll
    for (int r = 0; r < 4; ++r) { mst[r] = -1.0e30f; lst[r] = 0.f; }

    for (int kt = 0; kt < 10; ++kt) {
        __syncthreads();   // previous tile's Ks/Vt reads done before overwrite
        // ---- stage K tile [key][d] and V tile transposed+swizzled [d][key'] ----
        #pragma unroll
        for (int i = 0; i < 2; ++i) {
            int c = i * 256 + tid;
            int key = c >> 3, seg = c & 7;           // 8 segs of 8 bf16 per 64-elem row
            int gk = kt * 64 + key; if (gk >= NN) gk = NN - 1;
            const unsigned short* kb = qkv + (size_t)(b * NN + gk) * 2304 + 768 + h * 64 + seg * 8;
            bf16x8 kv = *(const bf16x8*)kb;
            *(bf16x8*)&Ks[key * 72 + seg * 8] = kv;
            const unsigned short* vb = qkv + (size_t)(b * NN + gk) * 2304 + 1536 + h * 64 + seg * 8;
            bf16x8 vvv = *(const bf16x8*)vb;
            int kg = key >> 3, kl = key & 7;
            int swz = (kg ^ seg) * 8 + kl;           // d>>3 == seg for d=seg*8+e
            #pragma unroll
            for (int e = 0; e < 8; ++e)
                Vt[(seg * 8 + e) * 72 + swz] = ((const unsigned short*)&vvv)[e];
        }
        __syncthreads();

        // ---- S = Q K^T (pre-scaled): s[ni][r] = S[quad*4+r][ni*16+l16] ----
        f32x4 s[4];
        #pragma unroll
        for (int ni = 0; ni < 4; ++ni) {
            bf16x8 b0 = *(const bf16x8*)&Ks[(ni * 16 + l16) * 72 + quad * 8];
            bf16x8 b1 = *(const bf16x8*)&Ks[(ni * 16 + l16) * 72 + 32 + quad * 8];
            f32x4 acc = {};
            acc = __builtin_amdgcn_mfma_f32_16x16x32_bf16(qf[0], b0, acc, 0, 0, 0);
            acc = __builtin_amdgcn_mfma_f32_16x16x32_bf16(qf[1], b1, acc, 0, 0, 0);
            s[ni] = acc;
        }

        // ---- mask invalid keys (only last tile; only key 576 is valid) ----
        if (kt == 9) {
            #pragma unroll
            for (int ni = 0; ni < 4; ++ni) {
                if (ni * 16 + l16 != 0) {
                    #pragma unroll
                    for (int r = 0; r < 4; ++r) s[ni][r] = -1.0e30f;
                }
            }
        }

        // ---- row 0 only: patch_attn extraction + attn_weight factor ----
        // global row 0 lives in qt==0, wv==0, quad==0, r==0; its 64 keys of
        // this tile are spread over the 16 quad-0 lanes x 4 ni groups.
        if (qt == 0 && wv == 0 && quad == 0) {
            #pragma unroll
            for (int ni = 0; ni < 4; ++ni) {
                int gkey = kt * 64 + ni * 16 + l16;
                if (gkey >= 1 && gkey < NN) {
                    patch[(size_t)(b * HH + h) * (NN - 1) + gkey - 1] = s[ni][0];
                    float f = aw[b * (NN - 1) + gkey - 1] * 0.1f + 0.9f;
                    s[ni][0] *= f;
                }
            }
        }

        // ---- online softmax, fully in-register ----
        float al[4];
        #pragma unroll
        for (int r = 0; r < 4; ++r) {
            float tm = fmaxf(fmaxf(s[0][r], s[1][r]), fmaxf(s[2][r], s[3][r]));
            tm = fmaxf(tm, __shfl_xor(tm, 1));
            tm = fmaxf(tm, __shfl_xor(tm, 2));
            tm = fmaxf(tm, __shfl_xor(tm, 4));
            tm = fmaxf(tm, __shfl_xor(tm, 8));
            float nm = fmaxf(mst[r], tm);
            al[r] = __expf(mst[r] - nm);   // first tile: exp(-1e30) -> 0
            mst[r] = nm;
        }
        #pragma unroll
        for (int r = 0; r < 4; ++r) {
            float rs = 0.f;
            #pragma unroll
            for (int ni = 0; ni < 4; ++ni) {
                float p = __expf(s[ni][r] - mst[r]);   // masked: exp(-1e30) -> 0
                Pt[wv][(quad * 4 + r) * 72 + ni * 16 + l16] = f2b(p);
                rs += p;
            }
            rs += __shfl_xor(rs, 1);
            rs += __shfl_xor(rs, 2);
            rs += __shfl_xor(rs, 4);
            rs += __shfl_xor(rs, 8);
            lst[r] = lst[r] * al[r] + rs;
            #pragma unroll
            for (int ni = 0; ni < 4; ++ni) o[ni][r] *= al[r];
        }

        // ---- O += P V ----
        #pragma unroll
        for (int kc = 0; kc < 2; ++kc) {
            bf16x8 af = *(const bf16x8*)&Pt[wv][l16 * 72 + kc * 32 + quad * 8];
            #pragma unroll
            for (int ni = 0; ni < 4; ++ni) {
                int d = ni * 16 + l16;
                int gs = (kc * 4 + quad) ^ (d >> 3);   // un-swizzle key group
                bf16x8 vf = *(const bf16x8*)&Vt[d * 72 + gs * 8];
                o[ni] = __builtin_amdgcn_mfma_f32_16x16x32_bf16(af, vf, o[ni], 0, 0, 0);
            }
        }
    }

    // ---- finalize: O /= l (per-lane row stats, no shuffle), store bf16 ----
    #pragma unroll
    for (int r = 0; r < 4; ++r) {
        float inv = (lst[r] > 0.f) ? __builtin_amdgcn_rcpf(lst[r]) : 0.f;
        int row = qt * 64 + wv * 16 + quad * 4 + r;
        if (row < NN) {
            #pragma unroll
            for (int ni = 0; ni < 4; ++ni)
                O[(size_t)(b * NN + row) * CC + h * 64 + ni * 16 + l16] = f2b(o[ni][r] * inv);
        }
    }
}

// ---------------------------------------------------------------------------
extern "C" void kernel_launch(void* const* d_in, const int* in_sizes, int n_in,
                              void* d_out, int out_size, void* d_ws, size_t ws_size,
                              hipStream_t stream) {
    const float* x       = (const float*)d_in[0];
    const float* aw      = (const float*)d_in[1];
    const float* ln1w    = (const float*)d_in[2];
    const float* ln1b    = (const float*)d_in[3];
    const float* qkvw_f  = (const float*)d_in[4];
    const float* qkvb    = (const float*)d_in[5];
    const float* projw_f = (const float*)d_in[6];
    const float* projb   = (const float*)d_in[7];
    const float* ln2w    = (const float*)d_in[8];
    const float* ln2b    = (const float*)d_in[9];
    const float* fc1w_f  = (const float*)d_in[10];
    const float* fc1b    = (const float*)d_in[11];
    const float* fc2w_f  = (const float*)d_in[12];
    const float* fc2b    = (const float*)d_in[13];

    // workspace layout (g1 aliases h_bf+qkv, both dead before FC1). ~240 MB.
    char* ws = (char*)d_ws;
    unsigned short* h_bf  = (unsigned short*)(ws + 0);            // 18464x768 bf16
    unsigned short* qkv   = (unsigned short*)(ws + 28360704);     // 18464x2304 bf16
    unsigned short* g1    = (unsigned short*)(ws + 0);            // 18464x3072 bf16 (alias)
    unsigned short* attno = (unsigned short*)(ws + 113442816);    // 18464x768 bf16
    float*          x1    = (float*)(ws + 141803520);             // 18464x768 f32
    unsigned short* h2    = (unsigned short*)(ws + 198524928);    // 18464x768 bf16
    unsigned short* qkvw  = (unsigned short*)(ws + 226885632);    // 2304x768 bf16
    unsigned short* projw = (unsigned short*)(ws + 230424576);    // 768x768 bf16
    unsigned short* fc1w  = (unsigned short*)(ws + 231604224);    // 3072x768 bf16
    unsigned short* fc2w  = (unsigned short*)(ws + 236322816);    // 768x3072 bf16

    float* out_x = (float*)d_out;
    float* out_patch = out_x + (size_t)MROWS * CC;

    // 152 = 8 * ceil(145 m-tiles / 8) -- padded for the XCD swizzle
    cvt4<<<1024, 256, 0, stream>>>(qkvw_f, 2304 * 768, qkvw,
                                   projw_f, 768 * 768, projw,
                                   fc1w_f, 3072 * 768, fc1w,
                                   fc2w_f, 768 * 3072, fc2w);
    ln_kernel<<<MROWS, 256, 0, stream>>>(x, ln1w, ln1b, h_bf);
    gemm_bt<0><<<dim3(18, 152), 256, 0, stream>>>(h_bf, qkvw, qkvb, nullptr, qkv, nullptr,
                                                  MROWS, 2304, 768);
    attn_mfma<<<dim3(10, HH, BB), 256, 0, stream>>>(qkv, aw, attno, out_patch);
    gemm_bt<2><<<dim3(6, 152), 256, 0, stream>>>(attno, projw, projb, x, nullptr, x1,
                                                 MROWS, 768, 768);
    ln_kernel<<<MROWS, 256, 0, stream>>>(x1, ln2w, ln2b, h2);
    gemm_bt<1><<<dim3(24, 152), 256, 0, stream>>>(h2, fc1w, fc1b, nullptr, g1, nullptr,
                                                  MROWS, 3072, 768);
    gemm_bt<2><<<dim3(6, 152), 256, 0, stream>>>(g1, fc2w, fc2b, x1, nullptr, out_x,
                                                 MROWS, 768, 3072);
}

// Round 4
// 709.525 us; speedup vs baseline: 1.1095x; 1.0600x over previous
//
#include <hip/hip_runtime.h>
#include <hip/hip_bf16.h>
#include <cstdint>

#define BB 32
#define NN 577
#define CC 768
#define HH 12
#define HIDN 3072
#define MROWS (BB*NN)   // 18464

typedef __attribute__((ext_vector_type(8))) short bf16x8;   // 8 bf16 = 4 VGPRs
typedef __attribute__((ext_vector_type(4))) float f32x4;

__device__ __forceinline__ float b2f(unsigned short u) {
    union { float f; unsigned int i; } x; x.i = ((unsigned int)u) << 16; return x.f;
}
__device__ __forceinline__ unsigned short f2b(float f) {
    union { float f; unsigned int i; } x; x.f = f;
    unsigned int i = x.i;
    i += 0x7fffu + ((i >> 16) & 1u);   // round-to-nearest-even
    return (unsigned short)(i >> 16);
}

__device__ __forceinline__ void async16(const void* g, void* l) {
    __builtin_amdgcn_global_load_lds(
        (const __attribute__((address_space(1))) uint32_t*)g,
        (__attribute__((address_space(3))) uint32_t*)l, 16, 0, 0);
}

// Fast exact-GELU: erf via Abramowitz-Stegun 7.1.26 (|err|<=1.5e-7),
// rcp + exp are single HW instrs. ~13 VALU vs ~45 for libm erff.
__device__ __forceinline__ float gelu_f(float v) {
    float ax = fabsf(v) * 0.70710678118654752f;
    float t = __builtin_amdgcn_rcpf(1.0f + 0.3275911f * ax);
    float poly = t * (0.254829592f + t * (-0.284496736f + t * (1.421413741f +
                 t * (-1.453152027f + t * 1.061405429f))));
    float e = __expf(-ax * ax);
    float erf_abs = 1.0f - poly * e;
    float erf_v = (v >= 0.f) ? erf_abs : -erf_abs;
    return 0.5f * v * (1.0f + erf_v);
}

// ---------------------------------------------------------------------------
// fp32 -> bf16 weight conversion (4 matrices in one kernel)
// ---------------------------------------------------------------------------
__global__ void cvt4(const float* __restrict__ a, int na, unsigned short* __restrict__ oa,
                     const float* __restrict__ b, int nb, unsigned short* __restrict__ ob,
                     const float* __restrict__ c, int nc, unsigned short* __restrict__ oc,
                     const float* __restrict__ d, int nd, unsigned short* __restrict__ od) {
    int stride = gridDim.x * blockDim.x;
    int t = blockIdx.x * blockDim.x + threadIdx.x;
    for (int i = t; i < na; i += stride) oa[i] = f2b(a[i]);
    for (int i = t; i < nb; i += stride) ob[i] = f2b(b[i]);
    for (int i = t; i < nc; i += stride) oc[i] = f2b(c[i]);
    for (int i = t; i < nd; i += stride) od[i] = f2b(d[i]);
}

// ---------------------------------------------------------------------------
// LayerNorm (row of 768), fp32 in -> bf16 out
// ---------------------------------------------------------------------------
__global__ __launch_bounds__(256)
void ln_kernel(const float* __restrict__ x, const float* __restrict__ w,
               const float* __restrict__ bsv, unsigned short* __restrict__ out) {
    int row = blockIdx.x;
    const float* xr = x + (size_t)row * CC;
    float v[3]; float s = 0.f, ss = 0.f;
    #pragma unroll
    for (int i = 0; i < 3; ++i) {
        v[i] = xr[threadIdx.x + i * 256];
        s += v[i]; ss += v[i] * v[i];
    }
    int lane = threadIdx.x & 63, wv = threadIdx.x >> 6;
    #pragma unroll
    for (int off = 32; off; off >>= 1) { s += __shfl_down(s, off); ss += __shfl_down(ss, off); }
    __shared__ float rs[4], rss[4];
    __shared__ float mean_s, rstd_s;
    if (lane == 0) { rs[wv] = s; rss[wv] = ss; }
    __syncthreads();
    if (threadIdx.x == 0) {
        float S = rs[0] + rs[1] + rs[2] + rs[3];
        float SS = rss[0] + rss[1] + rss[2] + rss[3];
        float m = S * (1.0f / 768.0f);
        float var = SS * (1.0f / 768.0f) - m * m;
        mean_s = m; rstd_s = rsqrtf(var + 1e-6f);
    }
    __syncthreads();
    float m = mean_s, r = rstd_s;
    #pragma unroll
    for (int i = 0; i < 3; ++i) {
        int c = threadIdx.x + i * 256;
        out[(size_t)row * CC + c] = f2b((v[i] - m) * r * w[c] + bsv[c]);
    }
}

// ---------------------------------------------------------------------------
// bf16 GEMM: out = epilogue(A(M,K) @ Bw(N,K)^T + bias)
// m97 structure, BK=64 as two 32-wide panels (As[2]/Bs[2], 32 KB LDS).
// R3: __launch_bounds__(256,4) -> <=128 unified regs/wave (64 VGPR + 64 AGPR)
// so 4 blocks/CU co-reside (was 3 at 144 regs). FC2's 912-block grid then
// fits one round (1024 capacity) instead of 768+144-block tail (~half the
// wall time at ~19% device util; measured Occupancy 20.2% == 2-round model).
// Inner loop restructured (bfr[4] + one af live = 20 frag regs, was 32) to
// give the allocator a legal <=64-VGPR schedule.
// EPI 0: bf16 store | 1: fast exact GELU -> bf16 | 2: fp32 store w/ residual
// Launch grid dim3(NT, 152): 152 = 8*ceil(145/8) padded m-rows.
// ---------------------------------------------------------------------------
template <int EPI>
__global__ __launch_bounds__(256, 4)
void gemm_bt(const unsigned short* __restrict__ A, const unsigned short* __restrict__ Bw,
             const float* __restrict__ bias, const float* __restrict__ resid,
             unsigned short* __restrict__ outb, float* __restrict__ outf,
             int M, int N, int K) {
    const int NT = gridDim.x;
    const int MT = (M + 127) >> 7;
    // dispatch-order flat id -> (m_tile, n_tile) with same-XCD A sharing
    int flat = blockIdx.y * NT + blockIdx.x;
    int xcd = flat & 7, s = flat >> 3;
    int n_t = s % NT, mj = s / NT;
    int m_t = xcd + 8 * mj;
    if (m_t >= MT) return;
    const int m0 = m_t * 128, n0 = n_t * 128;

    __shared__ __align__(16) unsigned short As[2][128 * 32];
    __shared__ __align__(16) unsigned short Bs[2][128 * 32];
    const int tid = threadIdx.x;
    const int wave = tid >> 6, lane = tid & 63;
    const int wr = wave >> 1, wc = wave & 1;
    const int quad = lane >> 4, l16 = lane & 15;

    f32x4 acc[4][4] = {};

    // per-thread staging coords (fixed across K): two chunks per panel/matrix
    const int c0 = tid, c1 = 256 + tid;
    const int row0 = c0 >> 2, seg0 = c0 & 3;
    const int row1 = c1 >> 2, seg1 = c1 & 3;
    int gm0 = m0 + row0; if (gm0 > M - 1) gm0 = M - 1;
    int gm1 = m0 + row1; if (gm1 > M - 1) gm1 = M - 1;
    const unsigned short* a0 = A + (size_t)gm0 * K + seg0 * 8;
    const unsigned short* a1 = A + (size_t)gm1 * K + seg1 * 8;
    const unsigned short* b0 = Bw + (size_t)(n0 + row0) * K + seg0 * 8;
    const unsigned short* b1 = Bw + (size_t)(n0 + row1) * K + seg1 * 8;

    for (int k0 = 0; k0 < K; k0 += 64) {
        #pragma unroll
        for (int p = 0; p < 2; ++p) {
            int kk = k0 + p * 32;
            async16(a0 + kk, &As[p][c0 * 8]);
            async16(a1 + kk, &As[p][c1 * 8]);
            async16(b0 + kk, &Bs[p][c0 * 8]);
            async16(b1 + kk, &Bs[p][c1 * 8]);
        }
        __syncthreads();
        #pragma unroll
        for (int p = 0; p < 2; ++p) {
            bf16x8 bfr[4];
            #pragma unroll
            for (int ni = 0; ni < 4; ++ni)
                bfr[ni] = *(const bf16x8*)&Bs[p][(wc * 64 + ni * 16 + l16) * 32 + quad * 8];
            #pragma unroll
            for (int mi = 0; mi < 4; ++mi) {
                bf16x8 af = *(const bf16x8*)&As[p][(wr * 64 + mi * 16 + l16) * 32 + quad * 8];
                #pragma unroll
                for (int ni = 0; ni < 4; ++ni)
                    acc[mi][ni] = __builtin_amdgcn_mfma_f32_16x16x32_bf16(af, bfr[ni], acc[mi][ni], 0, 0, 0);
            }
        }
        __syncthreads();
    }

    #pragma unroll
    for (int mi = 0; mi < 4; ++mi) {
        #pragma unroll
        for (int r = 0; r < 4; ++r) {
            int grow = m0 + wr * 64 + mi * 16 + quad * 4 + r;   // C/D: row=quad*4+reg
            if (grow >= M) continue;
            #pragma unroll
            for (int ni = 0; ni < 4; ++ni) {
                int gcol = n0 + wc * 64 + ni * 16 + l16;        // C/D: col=lane&15
                float v = acc[mi][ni][r] + bias[gcol];
                size_t idx = (size_t)grow * N + gcol;
                if (EPI == 0) {
                    outb[idx] = f2b(v);
                } else if (EPI == 1) {
                    outb[idx] = f2b(gelu_f(v));
                } else {
                    outf[idx] = resid[idx] + v;
                }
            }
        }
    }
}

// ---------------------------------------------------------------------------
// MFMA flash attention, v3: in-register online softmax.
// One block = (b, h, 64 q rows); 4 waves x 16 rows.
// S stays in the MFMA C/D register layout (lane quad,l16 holds
// S[row=quad*4+r][key=ni*16+l16]); row stats via intra-quad shfl_xor
// butterfly (16 lanes own all 64 keys of rows quad*4..quad*4+3).
// 0.125 scale folded into Q at load (power of 2 -> exact in bf16).
// P transposed for the PV A-fragment through Pt[row][key] (pitch 72):
// u16 scatter writes are 2-way (free), reads are one aligned b128 per kc.
// LDS 27.6KB: 5 blocks/CU.
// ---------------------------------------------------------------------------
__global__ __launch_bounds__(256)
void attn_mfma(const unsigned short* __restrict__ qkv, const float* __restrict__ aw,
               unsigned short* __restrict__ O, float* __restrict__ patch) {
    const int qt = blockIdx.x, h = blockIdx.y, b = blockIdx.z;
    const int tid = threadIdx.x, wv = tid >> 6, lane = tid & 63;
    const int quad = lane >> 4, l16 = lane & 15;

    __shared__ __align__(16) unsigned short Ks[64 * 72];
    __shared__ __align__(16) unsigned short Vt[64 * 72];
    __shared__ __align__(16) unsigned short Pt[4][16 * 72];

    // Q fragment (A-layout: m=l16, k=quad*8+j), resident, pre-scaled by 2^-3.
    int qrow = qt * 64 + wv * 16 + l16;
    int qclamp = qrow < NN ? qrow : NN - 1;
    const unsigned short* qbase = qkv + (size_t)(b * NN + qclamp) * 2304 + h * 64;
    bf16x8 qf[2];
    qf[0] = *(const bf16x8*)(qbase + quad * 8);
    qf[1] = *(const bf16x8*)(qbase + 32 + quad * 8);
    #pragma unroll
    for (int i = 0; i < 2; ++i) {
        union { bf16x8 v; unsigned short u[8]; } t; t.v = qf[i];
        #pragma unroll
        for (int j = 0; j < 8; ++j) t.u[j] = f2b(b2f(t.u[j]) * 0.125f);
        qf[i] = t.v;
    }

    f32x4 o[4] = {};          // O accumulator, C-layout (row=quad*4+r, col d=ni*16+l16)
    float mst[4], lst[4];     // per-row running max / denom (rows quad*4+r)
    #pragma unroll
    for (int r = 0; r < 4; ++r) { mst[r] = -1.0e30f; lst[r] = 0.f; }

    for (int kt = 0; kt < 10; ++kt) {
        __syncthreads();   // previous tile's Ks/Vt reads done before overwrite
        // ---- stage K tile [key][d] and V tile transposed+swizzled [d][key'] ----
        #pragma unroll
        for (int i = 0; i < 2; ++i) {
            int c = i * 256 + tid;
            int key = c >> 3, seg = c & 7;           // 8 segs of 8 bf16 per 64-elem row
            int gk = kt * 64 + key; if (gk >= NN) gk = NN - 1;
            const unsigned short* kb = qkv + (size_t)(b * NN + gk) * 2304 + 768 + h * 64 + seg * 8;
            bf16x8 kv = *(const bf16x8*)kb;
            *(bf16x8*)&Ks[key * 72 + seg * 8] = kv;
            const unsigned short* vb = qkv + (size_t)(b * NN + gk) * 2304 + 1536 + h * 64 + seg * 8;
            bf16x8 vvv = *(const bf16x8*)vb;
            int kg = key >> 3, kl = key & 7;
            int swz = (kg ^ seg) * 8 + kl;           // d>>3 == seg for d=seg*8+e
            #pragma unroll
            for (int e = 0; e < 8; ++e)
                Vt[(seg * 8 + e) * 72 + swz] = ((const unsigned short*)&vvv)[e];
        }
        __syncthreads();

        // ---- S = Q K^T (pre-scaled): s[ni][r] = S[quad*4+r][ni*16+l16] ----
        f32x4 s[4];
        #pragma unroll
        for (int ni = 0; ni < 4; ++ni) {
            bf16x8 b0 = *(const bf16x8*)&Ks[(ni * 16 + l16) * 72 + quad * 8];
            bf16x8 b1 = *(const bf16x8*)&Ks[(ni * 16 + l16) * 72 + 32 + quad * 8];
            f32x4 acc = {};
            acc = __builtin_amdgcn_mfma_f32_16x16x32_bf16(qf[0], b0, acc, 0, 0, 0);
            acc = __builtin_amdgcn_mfma_f32_16x16x32_bf16(qf[1], b1, acc, 0, 0, 0);
            s[ni] = acc;
        }

        // ---- mask invalid keys (only last tile; only key 576 is valid) ----
        if (kt == 9) {
            #pragma unroll
            for (int ni = 0; ni < 4; ++ni) {
                if (ni * 16 + l16 != 0) {
                    #pragma unroll
                    for (int r = 0; r < 4; ++r) s[ni][r] = -1.0e30f;
                }
            }
        }

        // ---- row 0 only: patch_attn extraction + attn_weight factor ----
        // global row 0 lives in qt==0, wv==0, quad==0, r==0; its 64 keys of
        // this tile are spread over the 16 quad-0 lanes x 4 ni groups.
        if (qt == 0 && wv == 0 && quad == 0) {
            #pragma unroll
            for (int ni = 0; ni < 4; ++ni) {
                int gkey = kt * 64 + ni * 16 + l16;
                if (gkey >= 1 && gkey < NN) {
                    patch[(size_t)(b * HH + h) * (NN - 1) + gkey - 1] = s[ni][0];
                    float f = aw[b * (NN - 1) + gkey - 1] * 0.1f + 0.9f;
                    s[ni][0] *= f;
                }
            }
        }

        // ---- online softmax, fully in-register ----
        float al[4];
        #pragma unroll
        for (int r = 0; r < 4; ++r) {
            float tm = fmaxf(fmaxf(s[0][r], s[1][r]), fmaxf(s[2][r], s[3][r]));
            tm = fmaxf(tm, __shfl_xor(tm, 1));
            tm = fmaxf(tm, __shfl_xor(tm, 2));
            tm = fmaxf(tm, __shfl_xor(tm, 4));
            tm = fmaxf(tm, __shfl_xor(tm, 8));
            float nm = fmaxf(mst[r], tm);
            al[r] = __expf(mst[r] - nm);   // first tile: exp(-1e30) -> 0
            mst[r] = nm;
        }
        #pragma unroll
        for (int r = 0; r < 4; ++r) {
            float rs = 0.f;
            #pragma unroll
            for (int ni = 0; ni < 4; ++ni) {
                float p = __expf(s[ni][r] - mst[r]);   // masked: exp(-1e30) -> 0
                Pt[wv][(quad * 4 + r) * 72 + ni * 16 + l16] = f2b(p);
                rs += p;
            }
            rs += __shfl_xor(rs, 1);
            rs += __shfl_xor(rs, 2);
            rs += __shfl_xor(rs, 4);
            rs += __shfl_xor(rs, 8);
            lst[r] = lst[r] * al[r] + rs;
            #pragma unroll
            for (int ni = 0; ni < 4; ++ni) o[ni][r] *= al[r];
        }

        // ---- O += P V ----
        #pragma unroll
        for (int kc = 0; kc < 2; ++kc) {
            bf16x8 af = *(const bf16x8*)&Pt[wv][l16 * 72 + kc * 32 + quad * 8];
            #pragma unroll
            for (int ni = 0; ni < 4; ++ni) {
                int d = ni * 16 + l16;
                int gs = (kc * 4 + quad) ^ (d >> 3);   // un-swizzle key group
                bf16x8 vf = *(const bf16x8*)&Vt[d * 72 + gs * 8];
                o[ni] = __builtin_amdgcn_mfma_f32_16x16x32_bf16(af, vf, o[ni], 0, 0, 0);
            }
        }
    }

    // ---- finalize: O /= l (per-lane row stats, no shuffle), store bf16 ----
    #pragma unroll
    for (int r = 0; r < 4; ++r) {
        float inv = (lst[r] > 0.f) ? __builtin_amdgcn_rcpf(lst[r]) : 0.f;
        int row = qt * 64 + wv * 16 + quad * 4 + r;
        if (row < NN) {
            #pragma unroll
            for (int ni = 0; ni < 4; ++ni)
                O[(size_t)(b * NN + row) * CC + h * 64 + ni * 16 + l16] = f2b(o[ni][r] * inv);
        }
    }
}

// ---------------------------------------------------------------------------
extern "C" void kernel_launch(void* const* d_in, const int* in_sizes, int n_in,
                              void* d_out, int out_size, void* d_ws, size_t ws_size,
                              hipStream_t stream) {
    const float* x       = (const float*)d_in[0];
    const float* aw      = (const float*)d_in[1];
    const float* ln1w    = (const float*)d_in[2];
    const float* ln1b    = (const float*)d_in[3];
    const float* qkvw_f  = (const float*)d_in[4];
    const float* qkvb    = (const float*)d_in[5];
    const float* projw_f = (const float*)d_in[6];
    const float* projb   = (const float*)d_in[7];
    const float* ln2w    = (const float*)d_in[8];
    const float* ln2b    = (const float*)d_in[9];
    const float* fc1w_f  = (const float*)d_in[10];
    const float* fc1b    = (const float*)d_in[11];
    const float* fc2w_f  = (const float*)d_in[12];
    const float* fc2b    = (const float*)d_in[13];

    // workspace layout (g1 aliases h_bf+qkv, both dead before FC1). ~240 MB.
    char* ws = (char*)d_ws;
    unsigned short* h_bf  = (unsigned short*)(ws + 0);            // 18464x768 bf16
    unsigned short* qkv   = (unsigned short*)(ws + 28360704);     // 18464x2304 bf16
    unsigned short* g1    = (unsigned short*)(ws + 0);            // 18464x3072 bf16 (alias)
    unsigned short* attno = (unsigned short*)(ws + 113442816);    // 18464x768 bf16
    float*          x1    = (float*)(ws + 141803520);             // 18464x768 f32
    unsigned short* h2    = (unsigned short*)(ws + 198524928);    // 18464x768 bf16
    unsigned short* qkvw  = (unsigned short*)(ws + 226885632);    // 2304x768 bf16
    unsigned short* projw = (unsigned short*)(ws + 230424576);    // 768x768 bf16
    unsigned short* fc1w  = (unsigned short*)(ws + 231604224);    // 3072x768 bf16
    unsigned short* fc2w  = (unsigned short*)(ws + 236322816);    // 768x3072 bf16

    float* out_x = (float*)d_out;
    float* out_patch = out_x + (size_t)MROWS * CC;

    // 152 = 8 * ceil(145 m-tiles / 8) -- padded for the XCD swizzle
    cvt4<<<1024, 256, 0, stream>>>(qkvw_f, 2304 * 768, qkvw,
                                   projw_f, 768 * 768, projw,
                                   fc1w_f, 3072 * 768, fc1w,
                                   fc2w_f, 768 * 3072, fc2w);
    ln_kernel<<<MROWS, 256, 0, stream>>>(x, ln1w, ln1b, h_bf);
    gemm_bt<0><<<dim3(18, 152), 256, 0, stream>>>(h_bf, qkvw, qkvb, nullptr, qkv, nullptr,
                                                  MROWS, 2304, 768);
    attn_mfma<<<dim3(10, HH, BB), 256, 0, stream>>>(qkv, aw, attno, out_patch);
    gemm_bt<2><<<dim3(6, 152), 256, 0, stream>>>(attno, projw, projb, x, nullptr, x1,
                                                 MROWS, 768, 768);
    ln_kernel<<<MROWS, 256, 0, stream>>>(x1, ln2w, ln2b, h2);
    gemm_bt<1><<<dim3(24, 152), 256, 0, stream>>>(h2, fc1w, fc1b, nullptr, g1, nullptr,
                                                  MROWS, 3072, 768);
    gemm_bt<2><<<dim3(6, 152), 256, 0, stream>>>(g1, fc2w, fc2b, x1, nullptr, out_x,
                                                 MROWS, 768, 3072);
}

// Round 5
// 682.703 us; speedup vs baseline: 1.1531x; 1.0393x over previous
//
#include <hip/hip_runtime.h>
#include <hip/hip_bf16.h>
#include <cstdint>

#define BB 32
#define NN 577
#define CC 768
#define HH 12
#define HIDN 3072
#define MROWS (BB*NN)   // 18464

typedef __attribute__((ext_vector_type(8))) short bf16x8;   // 8 bf16 = 4 VGPRs
typedef __attribute__((ext_vector_type(4))) float f32x4;

__device__ __forceinline__ float b2f(unsigned short u) {
    union { float f; unsigned int i; } x; x.i = ((unsigned int)u) << 16; return x.f;
}
__device__ __forceinline__ unsigned short f2b(float f) {
    union { float f; unsigned int i; } x; x.f = f;
    unsigned int i = x.i;
    i += 0x7fffu + ((i >> 16) & 1u);   // round-to-nearest-even
    return (unsigned short)(i >> 16);
}

__device__ __forceinline__ void async16(const void* g, void* l) {
    __builtin_amdgcn_global_load_lds(
        (const __attribute__((address_space(1))) uint32_t*)g,
        (__attribute__((address_space(3))) uint32_t*)l, 16, 0, 0);
}

// Fast exact-GELU: erf via Abramowitz-Stegun 7.1.26 (|err|<=1.5e-7),
// rcp + exp are single HW instrs. ~13 VALU vs ~45 for libm erff.
__device__ __forceinline__ float gelu_f(float v) {
    float ax = fabsf(v) * 0.70710678118654752f;
    float t = __builtin_amdgcn_rcpf(1.0f + 0.3275911f * ax);
    float poly = t * (0.254829592f + t * (-0.284496736f + t * (1.421413741f +
                 t * (-1.453152027f + t * 1.061405429f))));
    float e = __expf(-ax * ax);
    float erf_abs = 1.0f - poly * e;
    float erf_v = (v >= 0.f) ? erf_abs : -erf_abs;
    return 0.5f * v * (1.0f + erf_v);
}

// ---------------------------------------------------------------------------
// fp32 -> bf16 weight conversion (4 matrices in one kernel)
// ---------------------------------------------------------------------------
__global__ void cvt4(const float* __restrict__ a, int na, unsigned short* __restrict__ oa,
                     const float* __restrict__ b, int nb, unsigned short* __restrict__ ob,
                     const float* __restrict__ c, int nc, unsigned short* __restrict__ oc,
                     const float* __restrict__ d, int nd, unsigned short* __restrict__ od) {
    int stride = gridDim.x * blockDim.x;
    int t = blockIdx.x * blockDim.x + threadIdx.x;
    for (int i = t; i < na; i += stride) oa[i] = f2b(a[i]);
    for (int i = t; i < nb; i += stride) ob[i] = f2b(b[i]);
    for (int i = t; i < nc; i += stride) oc[i] = f2b(c[i]);
    for (int i = t; i < nd; i += stride) od[i] = f2b(d[i]);
}

// ---------------------------------------------------------------------------
// LayerNorm (row of 768), fp32 in -> bf16 out
// ---------------------------------------------------------------------------
__global__ __launch_bounds__(256)
void ln_kernel(const float* __restrict__ x, const float* __restrict__ w,
               const float* __restrict__ bsv, unsigned short* __restrict__ out) {
    int row = blockIdx.x;
    const float* xr = x + (size_t)row * CC;
    float v[3]; float s = 0.f, ss = 0.f;
    #pragma unroll
    for (int i = 0; i < 3; ++i) {
        v[i] = xr[threadIdx.x + i * 256];
        s += v[i]; ss += v[i] * v[i];
    }
    int lane = threadIdx.x & 63, wv = threadIdx.x >> 6;
    #pragma unroll
    for (int off = 32; off; off >>= 1) { s += __shfl_down(s, off); ss += __shfl_down(ss, off); }
    __shared__ float rs[4], rss[4];
    __shared__ float mean_s, rstd_s;
    if (lane == 0) { rs[wv] = s; rss[wv] = ss; }
    __syncthreads();
    if (threadIdx.x == 0) {
        float S = rs[0] + rs[1] + rs[2] + rs[3];
        float SS = rss[0] + rss[1] + rss[2] + rss[3];
        float m = S * (1.0f / 768.0f);
        float var = SS * (1.0f / 768.0f) - m * m;
        mean_s = m; rstd_s = rsqrtf(var + 1e-6f);
    }
    __syncthreads();
    float m = mean_s, r = rstd_s;
    #pragma unroll
    for (int i = 0; i < 3; ++i) {
        int c = threadIdx.x + i * 256;
        out[(size_t)row * CC + c] = f2b((v[i] - m) * r * w[c] + bsv[c]);
    }
}

// ---------------------------------------------------------------------------
// bf16 GEMM: out = epilogue(A(M,K) @ Bw(N,K)^T + bias)
// m97 structure, BK=64 as two 32-wide panels (As[2]/Bs[2], 32 KB LDS).
// R3: __launch_bounds__(256,4) -> <=128 unified regs/wave (64 VGPR + 64 AGPR)
// so 4 blocks/CU co-reside (was 3 at 144 regs); confirmed R4: gemms left
// the top-5, total -43 us.
// EPI 0: bf16 store | 1: fast exact GELU -> bf16 | 2: fp32 store w/ residual
// Launch grid dim3(NT, 152): 152 = 8*ceil(145/8) padded m-rows.
// ---------------------------------------------------------------------------
template <int EPI>
__global__ __launch_bounds__(256, 4)
void gemm_bt(const unsigned short* __restrict__ A, const unsigned short* __restrict__ Bw,
             const float* __restrict__ bias, const float* __restrict__ resid,
             unsigned short* __restrict__ outb, float* __restrict__ outf,
             int M, int N, int K) {
    const int NT = gridDim.x;
    const int MT = (M + 127) >> 7;
    // dispatch-order flat id -> (m_tile, n_tile) with same-XCD A sharing
    int flat = blockIdx.y * NT + blockIdx.x;
    int xcd = flat & 7, s = flat >> 3;
    int n_t = s % NT, mj = s / NT;
    int m_t = xcd + 8 * mj;
    if (m_t >= MT) return;
    const int m0 = m_t * 128, n0 = n_t * 128;

    __shared__ __align__(16) unsigned short As[2][128 * 32];
    __shared__ __align__(16) unsigned short Bs[2][128 * 32];
    const int tid = threadIdx.x;
    const int wave = tid >> 6, lane = tid & 63;
    const int wr = wave >> 1, wc = wave & 1;
    const int quad = lane >> 4, l16 = lane & 15;

    f32x4 acc[4][4] = {};

    // per-thread staging coords (fixed across K): two chunks per panel/matrix
    const int c0 = tid, c1 = 256 + tid;
    const int row0 = c0 >> 2, seg0 = c0 & 3;
    const int row1 = c1 >> 2, seg1 = c1 & 3;
    int gm0 = m0 + row0; if (gm0 > M - 1) gm0 = M - 1;
    int gm1 = m0 + row1; if (gm1 > M - 1) gm1 = M - 1;
    const unsigned short* a0 = A + (size_t)gm0 * K + seg0 * 8;
    const unsigned short* a1 = A + (size_t)gm1 * K + seg1 * 8;
    const unsigned short* b0 = Bw + (size_t)(n0 + row0) * K + seg0 * 8;
    const unsigned short* b1 = Bw + (size_t)(n0 + row1) * K + seg1 * 8;

    for (int k0 = 0; k0 < K; k0 += 64) {
        #pragma unroll
        for (int p = 0; p < 2; ++p) {
            int kk = k0 + p * 32;
            async16(a0 + kk, &As[p][c0 * 8]);
            async16(a1 + kk, &As[p][c1 * 8]);
            async16(b0 + kk, &Bs[p][c0 * 8]);
            async16(b1 + kk, &Bs[p][c1 * 8]);
        }
        __syncthreads();
        #pragma unroll
        for (int p = 0; p < 2; ++p) {
            bf16x8 bfr[4];
            #pragma unroll
            for (int ni = 0; ni < 4; ++ni)
                bfr[ni] = *(const bf16x8*)&Bs[p][(wc * 64 + ni * 16 + l16) * 32 + quad * 8];
            #pragma unroll
            for (int mi = 0; mi < 4; ++mi) {
                bf16x8 af = *(const bf16x8*)&As[p][(wr * 64 + mi * 16 + l16) * 32 + quad * 8];
                #pragma unroll
                for (int ni = 0; ni < 4; ++ni)
                    acc[mi][ni] = __builtin_amdgcn_mfma_f32_16x16x32_bf16(af, bfr[ni], acc[mi][ni], 0, 0, 0);
            }
        }
        __syncthreads();
    }

    #pragma unroll
    for (int mi = 0; mi < 4; ++mi) {
        #pragma unroll
        for (int r = 0; r < 4; ++r) {
            int grow = m0 + wr * 64 + mi * 16 + quad * 4 + r;   // C/D: row=quad*4+reg
            if (grow >= M) continue;
            #pragma unroll
            for (int ni = 0; ni < 4; ++ni) {
                int gcol = n0 + wc * 64 + ni * 16 + l16;        // C/D: col=lane&15
                float v = acc[mi][ni][r] + bias[gcol];
                size_t idx = (size_t)grow * N + gcol;
                if (EPI == 0) {
                    outb[idx] = f2b(v);
                } else if (EPI == 1) {
                    outb[idx] = f2b(gelu_f(v));
                } else {
                    outf[idx] = resid[idx] + v;
                }
            }
        }
    }
}

// ---------------------------------------------------------------------------
// MFMA flash attention, v4.
// v3 (R2): in-register online softmax (S in C/D layout, intra-quad butterflies).
// v4 (R4):
//  (a) ones-column PV: extra MFMA per kc with synthesized B-frag
//      (l16==0 ? 1.0 : 0) accumulates the P row-sum into o5 col 0 --
//      kills the 16 shfl_xor sum-butterfly + lst bookkeeping per tile;
//      alpha-rescale of l folds into the o5 rescale; denominator now uses
//      the SAME bf16 P as the numerator (more self-consistent).
//  (b) T14 async-stage split: K/V tile kt+1 global loads issue before
//      compute of kt (regs), LDS scatter happens after the next barrier --
//      HBM latency hides under ~2K cyc of compute.
//  (c) s_setprio(1) around MFMA clusters (5 blocks/CU at skewed phases).
// LDS 27.6KB: 5 blocks/CU.
// ---------------------------------------------------------------------------
__global__ __launch_bounds__(256)
void attn_mfma(const unsigned short* __restrict__ qkv, const float* __restrict__ aw,
               unsigned short* __restrict__ O, float* __restrict__ patch) {
    const int qt = blockIdx.x, h = blockIdx.y, b = blockIdx.z;
    const int tid = threadIdx.x, wv = tid >> 6, lane = tid & 63;
    const int quad = lane >> 4, l16 = lane & 15;

    __shared__ __align__(16) unsigned short Ks[64 * 72];
    __shared__ __align__(16) unsigned short Vt[64 * 72];
    __shared__ __align__(16) unsigned short Pt[4][16 * 72];

    // Q fragment (A-layout: m=l16, k=quad*8+j), resident, pre-scaled by 2^-3.
    int qrow = qt * 64 + wv * 16 + l16;
    int qclamp = qrow < NN ? qrow : NN - 1;
    const unsigned short* qbase = qkv + (size_t)(b * NN + qclamp) * 2304 + h * 64;
    bf16x8 qf[2];
    qf[0] = *(const bf16x8*)(qbase + quad * 8);
    qf[1] = *(const bf16x8*)(qbase + 32 + quad * 8);
    #pragma unroll
    for (int i = 0; i < 2; ++i) {
        union { bf16x8 v; unsigned short u[8]; } t; t.v = qf[i];
        #pragma unroll
        for (int j = 0; j < 8; ++j) t.u[j] = f2b(b2f(t.u[j]) * 0.125f);
        qf[i] = t.v;
    }

    // ones B-fragment for the l-column: B[n=0][k]=1, else 0.
    union { bf16x8 v; unsigned short u[8]; } onesf;
    #pragma unroll
    for (int j = 0; j < 8; ++j) onesf.u[j] = (l16 == 0) ? (unsigned short)0x3F80 : (unsigned short)0;

    f32x4 o[4] = {};          // O accumulator, C-layout (row=quad*4+r, col d=ni*16+l16)
    f32x4 o5 = {};            // l accumulator (col 0 = row-sum of P)
    float mst[4];             // per-row running max (rows quad*4+r)
    #pragma unroll
    for (int r = 0; r < 4; ++r) mst[r] = -1.0e30f;

    // per-thread staging coords (fixed across kt)
    int keyc[2], segc[2], swzc[2];
    const unsigned short* kb_base;
    const unsigned short* vb_base;
    {
        int c0 = tid, c1 = 256 + tid;
        keyc[0] = c0 >> 3; segc[0] = c0 & 7;
        keyc[1] = c1 >> 3; segc[1] = c1 & 7;
        #pragma unroll
        for (int i = 0; i < 2; ++i) {
            int kg = keyc[i] >> 3, kl = keyc[i] & 7;
            swzc[i] = (kg ^ segc[i]) * 8 + kl;
        }
        kb_base = qkv + (size_t)b * NN * 2304 + 768 + h * 64;
        vb_base = qkv + (size_t)b * NN * 2304 + 1536 + h * 64;
    }

    // prefetch tile 0 into regs
    bf16x8 pk[2], pv[2];
    #pragma unroll
    for (int i = 0; i < 2; ++i) {
        int gk = keyc[i]; if (gk >= NN) gk = NN - 1;   // kt=0: always < NN
        pk[i] = *(const bf16x8*)(kb_base + (size_t)gk * 2304 + segc[i] * 8);
        pv[i] = *(const bf16x8*)(vb_base + (size_t)gk * 2304 + segc[i] * 8);
    }

    for (int kt = 0; kt < 10; ++kt) {
        __syncthreads();   // previous tile's Ks/Vt/Pt reads done before overwrite
        // ---- scatter prefetched K tile [key][d], V transposed+swizzled [d][key'] ----
        #pragma unroll
        for (int i = 0; i < 2; ++i) {
            *(bf16x8*)&Ks[keyc[i] * 72 + segc[i] * 8] = pk[i];
            union { bf16x8 v; unsigned short u[8]; } t; t.v = pv[i];
            #pragma unroll
            for (int e = 0; e < 8; ++e)
                Vt[(segc[i] * 8 + e) * 72 + swzc[i]] = t.u[e];
        }
        __syncthreads();

        // ---- issue next tile's loads early (consumed after next barrier) ----
        if (kt < 9) {
            #pragma unroll
            for (int i = 0; i < 2; ++i) {
                int gk = (kt + 1) * 64 + keyc[i]; if (gk >= NN) gk = NN - 1;
                pk[i] = *(const bf16x8*)(kb_base + (size_t)gk * 2304 + segc[i] * 8);
                pv[i] = *(const bf16x8*)(vb_base + (size_t)gk * 2304 + segc[i] * 8);
            }
        }

        // ---- S = Q K^T (pre-scaled): s[ni][r] = S[quad*4+r][ni*16+l16] ----
        f32x4 s[4];
        __builtin_amdgcn_s_setprio(1);
        #pragma unroll
        for (int ni = 0; ni < 4; ++ni) {
            bf16x8 b0 = *(const bf16x8*)&Ks[(ni * 16 + l16) * 72 + quad * 8];
            bf16x8 b1 = *(const bf16x8*)&Ks[(ni * 16 + l16) * 72 + 32 + quad * 8];
            f32x4 acc = {};
            acc = __builtin_amdgcn_mfma_f32_16x16x32_bf16(qf[0], b0, acc, 0, 0, 0);
            acc = __builtin_amdgcn_mfma_f32_16x16x32_bf16(qf[1], b1, acc, 0, 0, 0);
            s[ni] = acc;
        }
        __builtin_amdgcn_s_setprio(0);

        // ---- mask invalid keys (only last tile; only key 576 is valid) ----
        if (kt == 9) {
            #pragma unroll
            for (int ni = 0; ni < 4; ++ni) {
                if (ni * 16 + l16 != 0) {
                    #pragma unroll
                    for (int r = 0; r < 4; ++r) s[ni][r] = -1.0e30f;
                }
            }
        }

        // ---- row 0 only: patch_attn extraction + attn_weight factor ----
        if (qt == 0 && wv == 0 && quad == 0) {
            #pragma unroll
            for (int ni = 0; ni < 4; ++ni) {
                int gkey = kt * 64 + ni * 16 + l16;
                if (gkey >= 1 && gkey < NN) {
                    patch[(size_t)(b * HH + h) * (NN - 1) + gkey - 1] = s[ni][0];
                    float f = aw[b * (NN - 1) + gkey - 1] * 0.1f + 0.9f;
                    s[ni][0] *= f;
                }
            }
        }

        // ---- online softmax: max via intra-quad butterfly; sums via o5 MFMA ----
        float al[4];
        #pragma unroll
        for (int r = 0; r < 4; ++r) {
            float tm = fmaxf(fmaxf(s[0][r], s[1][r]), fmaxf(s[2][r], s[3][r]));
            tm = fmaxf(tm, __shfl_xor(tm, 1));
            tm = fmaxf(tm, __shfl_xor(tm, 2));
            tm = fmaxf(tm, __shfl_xor(tm, 4));
            tm = fmaxf(tm, __shfl_xor(tm, 8));
            float nm = fmaxf(mst[r], tm);
            al[r] = __expf(mst[r] - nm);   // first tile: exp(-1e30) -> 0
            mst[r] = nm;
        }
        #pragma unroll
        for (int r = 0; r < 4; ++r) {
            #pragma unroll
            for (int ni = 0; ni < 4; ++ni) {
                float p = __expf(s[ni][r] - mst[r]);   // masked: exp(-1e30) -> 0
                Pt[wv][(quad * 4 + r) * 72 + ni * 16 + l16] = f2b(p);
            }
            #pragma unroll
            for (int ni = 0; ni < 4; ++ni) o[ni][r] *= al[r];
            o5[r] *= al[r];
        }

        // ---- O += P V ; l-column += P 1 ----
        __builtin_amdgcn_s_setprio(1);
        #pragma unroll
        for (int kc = 0; kc < 2; ++kc) {
            bf16x8 af = *(const bf16x8*)&Pt[wv][l16 * 72 + kc * 32 + quad * 8];
            #pragma unroll
            for (int ni = 0; ni < 4; ++ni) {
                int d = ni * 16 + l16;
                int gs = (kc * 4 + quad) ^ (d >> 3);   // un-swizzle key group
                bf16x8 vf = *(const bf16x8*)&Vt[d * 72 + gs * 8];
                o[ni] = __builtin_amdgcn_mfma_f32_16x16x32_bf16(af, vf, o[ni], 0, 0, 0);
            }
            o5 = __builtin_amdgcn_mfma_f32_16x16x32_bf16(af, onesf.v, o5, 0, 0, 0);
        }
        __builtin_amdgcn_s_setprio(0);
    }

    // ---- finalize: l for row quad*4+r lives in lane (quad,0) col 0 of o5 ----
    #pragma unroll
    for (int r = 0; r < 4; ++r) {
        float lr = __shfl(o5[r], quad << 4);
        float inv = (lr > 0.f) ? __builtin_amdgcn_rcpf(lr) : 0.f;
        int row = qt * 64 + wv * 16 + quad * 4 + r;
        if (row < NN) {
            #pragma unroll
            for (int ni = 0; ni < 4; ++ni)
                O[(size_t)(b * NN + row) * CC + h * 64 + ni * 16 + l16] = f2b(o[ni][r] * inv);
        }
    }
}

// ---------------------------------------------------------------------------
extern "C" void kernel_launch(void* const* d_in, const int* in_sizes, int n_in,
                              void* d_out, int out_size, void* d_ws, size_t ws_size,
                              hipStream_t stream) {
    const float* x       = (const float*)d_in[0];
    const float* aw      = (const float*)d_in[1];
    const float* ln1w    = (const float*)d_in[2];
    const float* ln1b    = (const float*)d_in[3];
    const float* qkvw_f  = (const float*)d_in[4];
    const float* qkvb    = (const float*)d_in[5];
    const float* projw_f = (const float*)d_in[6];
    const float* projb   = (const float*)d_in[7];
    const float* ln2w    = (const float*)d_in[8];
    const float* ln2b    = (const float*)d_in[9];
    const float* fc1w_f  = (const float*)d_in[10];
    const float* fc1b    = (const float*)d_in[11];
    const float* fc2w_f  = (const float*)d_in[12];
    const float* fc2b    = (const float*)d_in[13];

    // workspace layout (g1 aliases h_bf+qkv, both dead before FC1). ~240 MB.
    char* ws = (char*)d_ws;
    unsigned short* h_bf  = (unsigned short*)(ws + 0);            // 18464x768 bf16
    unsigned short* qkv   = (unsigned short*)(ws + 28360704);     // 18464x2304 bf16
    unsigned short* g1    = (unsigned short*)(ws + 0);            // 18464x3072 bf16 (alias)
    unsigned short* attno = (unsigned short*)(ws + 113442816);    // 18464x768 bf16
    float*          x1    = (float*)(ws + 141803520);             // 18464x768 f32
    unsigned short* h2    = (unsigned short*)(ws + 198524928);    // 18464x768 bf16
    unsigned short* qkvw  = (unsigned short*)(ws + 226885632);    // 2304x768 bf16
    unsigned short* projw = (unsigned short*)(ws + 230424576);    // 768x768 bf16
    unsigned short* fc1w  = (unsigned short*)(ws + 231604224);    // 3072x768 bf16
    unsigned short* fc2w  = (unsigned short*)(ws + 236322816);    // 768x3072 bf16

    float* out_x = (float*)d_out;
    float* out_patch = out_x + (size_t)MROWS * CC;

    // 152 = 8 * ceil(145 m-tiles / 8) -- padded for the XCD swizzle
    cvt4<<<1024, 256, 0, stream>>>(qkvw_f, 2304 * 768, qkvw,
                                   projw_f, 768 * 768, projw,
                                   fc1w_f, 3072 * 768, fc1w,
                                   fc2w_f, 768 * 3072, fc2w);
    ln_kernel<<<MROWS, 256, 0, stream>>>(x, ln1w, ln1b, h_bf);
    gemm_bt<0><<<dim3(18, 152), 256, 0, stream>>>(h_bf, qkvw, qkvb, nullptr, qkv, nullptr,
                                                  MROWS, 2304, 768);
    attn_mfma<<<dim3(10, HH, BB), 256, 0, stream>>>(qkv, aw, attno, out_patch);
    gemm_bt<2><<<dim3(6, 152), 256, 0, stream>>>(attno, projw, projb, x, nullptr, x1,
                                                 MROWS, 768, 768);
    ln_kernel<<<MROWS, 256, 0, stream>>>(x1, ln2w, ln2b, h2);
    gemm_bt<1><<<dim3(24, 152), 256, 0, stream>>>(h2, fc1w, fc1b, nullptr, g1, nullptr,
                                                  MROWS, 3072, 768);
    gemm_bt<2><<<dim3(6, 152), 256, 0, stream>>>(g1, fc2w, fc2b, x1, nullptr, out_x,
                                                 MROWS, 768, 3072);
}